// Round 9
// baseline (353.914 us; speedup 1.0000x reference)
//
#include <hip/hip_runtime.h>

#define N_NODES_C 50000
#define N_EDGES_C 800000
#define DIM 128
#define NCLS 40
#define SCAN_NB ((N_NODES_C + 255) / 256)      // 196
#define F2B_NB ((N_NODES_C * DIM / 4) / 256)   // 6250 (exact)
#define NBUK 32
#define BCAP 32768                              // >= 25000 + 50 sigma

typedef __attribute__((ext_vector_type(8))) short bf16x8;
typedef __attribute__((ext_vector_type(4))) float f32x4;

__device__ inline float bf2f(unsigned short u) {
    union { unsigned int i; float f; } c;
    c.i = ((unsigned int)u) << 16;
    return c.f;
}
__device__ inline unsigned short f2bf(float f) {
    union { float f; unsigned int i; } c;
    c.f = f;
    unsigned int x = c.i;
    x += 0x7fffu + ((x >> 16) & 1u);   // RNE
    return (unsigned short)(x >> 16);
}
// unpack 8 bf16 (one uint4) -> 8 fp32
__device__ inline void unp8(const uint4& g, float* f) {
    f[0] = __uint_as_float(g.x << 16); f[1] = __uint_as_float(g.x & 0xFFFF0000u);
    f[2] = __uint_as_float(g.y << 16); f[3] = __uint_as_float(g.y & 0xFFFF0000u);
    f[4] = __uint_as_float(g.z << 16); f[5] = __uint_as_float(g.z & 0xFFFF0000u);
    f[6] = __uint_as_float(g.w << 16); f[7] = __uint_as_float(g.w & 0xFFFF0000u);
}

// ---------------------------------------------------------------------------
// fused preprocessing: [0,F2B_NB) X->bf16 ; [F2B_NB,+64) W->bf16 ; last 4: scales
__global__ __launch_bounds__(256) void k_pre(const float* __restrict__ X,
                                             const float* __restrict__ W0,
                                             const float* __restrict__ W1,
                                             const float* __restrict__ W2,
                                             const float* __restrict__ W3,
                                             unsigned short* __restrict__ Xb,
                                             unsigned short* __restrict__ Wb,
                                             float* __restrict__ scale_inv) {
    int b = blockIdx.x;
    if (b < F2B_NB) {
        int i = b * 256 + threadIdx.x;
        float4 v = reinterpret_cast<const float4*>(X)[i];
        reinterpret_cast<ushort4*>(Xb)[i] =
            make_ushort4(f2bf(v.x), f2bf(v.y), f2bf(v.z), f2bf(v.w));
        return;
    }
    b -= F2B_NB;
    if (b < 64) {
        int m = b >> 4;
        int idx = (b & 15) * 256 + threadIdx.x;
        const float* W = m == 0 ? W0 : m == 1 ? W1 : m == 2 ? W2 : W3;
        float4 v = reinterpret_cast<const float4*>(W)[idx];
        reinterpret_cast<ushort4*>(Wb + (size_t)m * DIM * DIM)[idx] =
            make_ushort4(f2bf(v.x), f2bf(v.y), f2bf(v.z), f2bf(v.w));
        return;
    }
    b -= 64;
    const float* W = b == 0 ? W0 : b == 1 ? W1 : b == 2 ? W2 : W3;
    float s = 0.f;
    for (int i = threadIdx.x; i < DIM * DIM; i += 256) {
        float v = W[i];
        s += v * v;
    }
    #pragma unroll
    for (int off = 32; off >= 1; off >>= 1) s += __shfl_down(s, off);
    __shared__ float red[4];
    int lane = threadIdx.x & 63, wid = threadIdx.x >> 6;
    if (lane == 0) red[wid] = s;
    __syncthreads();
    if (threadIdx.x == 0) {
        float tot = red[0] + red[1] + red[2] + red[3];
        scale_inv[b] = 1.0f / sqrtf(tot);
    }
}

// ---------------------------------------------------------------------------
// multisplit edges into NBUK dst-range buckets; packed (dst<<16)|src.
__global__ __launch_bounds__(256) void k_bucket(const int* __restrict__ A,
                                                int* __restrict__ gcount,
                                                unsigned int* __restrict__ ebuk, int E) {
    __shared__ int cnt[NBUK];
    __shared__ int gbase[NBUK];
    int tid = threadIdx.x;
    if (tid < NBUK) cnt[tid] = 0;
    __syncthreads();
    int e0 = blockIdx.x * 1024;
    int s[4], d[4], b[4], r[4];
    #pragma unroll
    for (int j = 0; j < 4; ++j) {
        int e = e0 + j * 256 + tid;
        if (e < E) {
            s[j] = A[e];
            d[j] = A[E + e];
            b[j] = (int)(((unsigned long long)(unsigned)d[j] * NBUK) / N_NODES_C);
            r[j] = atomicAdd(&cnt[b[j]], 1);
        } else {
            b[j] = -1;
        }
    }
    __syncthreads();
    if (tid < NBUK) gbase[tid] = atomicAdd(&gcount[tid], cnt[tid]);
    __syncthreads();
    #pragma unroll
    for (int j = 0; j < 4; ++j) {
        if (b[j] >= 0) {
            int pos = gbase[b[j]] + r[j];
            if (pos < BCAP)
                ebuk[(size_t)b[j] * BCAP + pos] =
                    ((unsigned)d[j] << 16) | (unsigned)s[j];
        }
    }
}

// per-bucket degree histogram in LDS (replaces 800k global atomics)
__global__ __launch_bounds__(256) void k_degb(const unsigned int* __restrict__ ebuk,
                                              const int* __restrict__ gcount,
                                              int* __restrict__ deg) {
    int k = blockIdx.x;
    int base = (k * N_NODES_C + NBUK - 1) / NBUK;
    int next = ((k + 1) * N_NODES_C + NBUK - 1) / NBUK;
    int sz = next - base;                 // <= 1563
    __shared__ int dl[1568];
    for (int i = threadIdx.x; i < sz; i += 256) dl[i] = 0;
    __syncthreads();
    int count = gcount[k];
    if (count > BCAP) count = BCAP;
    for (int i = threadIdx.x; i < count; i += 256) {
        int d = (int)(ebuk[(size_t)k * BCAP + i] >> 16);
        atomicAdd(&dl[d - base], 1);
    }
    __syncthreads();
    for (int i = threadIdx.x; i < sz; i += 256) deg[base + i] = dl[i];
}

// scan phase 1: per-block sums (coalesced), dinv, and fill=0 init
__global__ __launch_bounds__(256) void k_scan_part(const int* __restrict__ cnt,
                                                   int* __restrict__ partial,
                                                   float* __restrict__ dinv,
                                                   int* __restrict__ fill, int n) {
    int idx = blockIdx.x * 256 + threadIdx.x;
    int v = (idx < n) ? cnt[idx] : 0;
    if (idx < n) {
        dinv[idx] = rsqrtf((float)v + 1.0f);
        fill[idx] = 0;
    }
    int s = v;
    #pragma unroll
    for (int off = 32; off >= 1; off >>= 1) s += __shfl_down(s, off);
    __shared__ int red[4];
    int lane = threadIdx.x & 63, wid = threadIdx.x >> 6;
    if (lane == 0) red[wid] = s;
    __syncthreads();
    if (threadIdx.x == 0) partial[blockIdx.x] = red[0] + red[1] + red[2] + red[3];
}

// scan phase 2 (fused): block base from partials + per-element scan -> ptr
__global__ __launch_bounds__(256) void k_scan_final(const int* __restrict__ cnt,
                                                    const int* __restrict__ partial,
                                                    int* __restrict__ ptr, int n, int nb) {
    int tid = threadIdx.x, bid = blockIdx.x;
    int lane = tid & 63, wid = tid >> 6;
    int pv = (tid < nb) ? partial[tid] : 0;
    int vb = (tid < bid) ? pv : 0;
    int s1 = vb, s2 = pv;
    #pragma unroll
    for (int off = 32; off >= 1; off >>= 1) {
        s1 += __shfl_down(s1, off);
        s2 += __shfl_down(s2, off);
    }
    __shared__ int r1[4], r2[4];
    if (lane == 0) { r1[wid] = s1; r2[wid] = s2; }
    __syncthreads();
    __shared__ int sbase, stot;
    if (tid == 0) {
        sbase = r1[0] + r1[1] + r1[2] + r1[3];
        stot  = r2[0] + r2[1] + r2[2] + r2[3];
    }
    __syncthreads();
    int idx = bid * 256 + tid;
    int v = (idx < n) ? cnt[idx] : 0;
    int sc = v;
    #pragma unroll
    for (int off = 1; off < 64; off <<= 1) {
        int t = __shfl_up(sc, off);
        if (lane >= off) sc += t;
    }
    __shared__ int wsum[4], wpre[4];
    if (lane == 63) wsum[wid] = sc;
    __syncthreads();
    if (tid == 0) {
        int acc = 0;
        #pragma unroll
        for (int w = 0; w < 4; ++w) { wpre[w] = acc; acc += wsum[w]; }
    }
    __syncthreads();
    if (idx < n) ptr[idx] = sbase + wpre[wid] + sc - v;
    if (bid == 0 && tid == 0) ptr[n] = stot;
}

// fill phase: bucket k handled by blocks bid%NBUK==k -> bid%8 XCD affinity;
// esrc slice (~50KB) + fill slice stay in one XCD's L2.
__global__ __launch_bounds__(256) void k_fillb(const unsigned int* __restrict__ ebuk,
                                               const int* __restrict__ gcount,
                                               const int* __restrict__ ptr,
                                               int* __restrict__ fill,
                                               unsigned short* __restrict__ esrc) {
    int k = blockIdx.x & (NBUK - 1);
    int c = blockIdx.x / NBUK;
    int count = gcount[k];
    if (count > BCAP) count = BCAP;
    int i0 = c * 1024;
    if (i0 >= count) return;
    #pragma unroll
    for (int j = 0; j < 4; ++j) {
        int i = i0 + j * 256 + threadIdx.x;
        if (i < count) {
            unsigned v = ebuk[(size_t)k * BCAP + i];
            int d = (int)(v >> 16);
            int s = (int)(v & 0xFFFFu);
            int pos = ptr[d] + atomicAdd(&fill[d], 1);
            esrc[pos] = (unsigned short)s;
        }
    }
}

// ---------------------------------------------------------------------------
// bf16 MFMA GEMM with dinv-prescale epilogue:
//   Gb[n][o] = bf16(dinv[n] * scale * sum_k Xb[n][k] * Wb[o][k])
__global__ __launch_bounds__(256) void k_gemm_mfma(const unsigned short* __restrict__ Xb,
                                                   const unsigned short* __restrict__ Wb,
                                                   const float* __restrict__ scale_ptr,
                                                   const float* __restrict__ dinv,
                                                   unsigned short* __restrict__ Gb, int N) {
    int tid = threadIdx.x;
    int w = tid >> 6;
    int l = tid & 63;
    int l15 = l & 15;
    int lg = l >> 4;
    int arow = blockIdx.x * 64 + w * 16 + l15;
    if (arow >= N) arow = N - 1;
    float scale = scale_ptr[0];

    f32x4 acc[8];
    #pragma unroll
    for (int ct = 0; ct < 8; ++ct) acc[ct] = f32x4{0.f, 0.f, 0.f, 0.f};

    #pragma unroll
    for (int kc = 0; kc < 4; ++kc) {
        int ko = kc * 32 + lg * 8;
        bf16x8 a = *reinterpret_cast<const bf16x8*>(&Xb[(size_t)arow * DIM + ko]);
        #pragma unroll
        for (int ct = 0; ct < 8; ++ct) {
            bf16x8 b = *reinterpret_cast<const bf16x8*>(&Wb[(size_t)(ct * 16 + l15) * DIM + ko]);
            acc[ct] = __builtin_amdgcn_mfma_f32_16x16x32_bf16(a, b, acc[ct], 0, 0, 0);
        }
    }
    int outrow0 = blockIdx.x * 64 + w * 16 + lg * 4;
    #pragma unroll
    for (int r = 0; r < 4; ++r) {
        int row = outrow0 + r;
        if (row < N) {
            float dv = dinv[row] * scale;
            #pragma unroll
            for (int ct = 0; ct < 8; ++ct)
                Gb[(size_t)row * DIM + ct * 16 + l15] = f2bf(acc[ct][r] * dv);
        }
    }
}

// ---------------------------------------------------------------------------
// aggregation: one node per WAVE; 4 edges per gather instruction.
// lane l: edge group grp=l>>4, row chunk li=l&15 (16B of the 256B row).
// out = dinv[n]*(sum_edges G[src] + G[n]) + b  (+relu+skip), bf16 in/out.
__global__ __launch_bounds__(256) void k_agg(const unsigned short* __restrict__ Gb,
                                             const float* __restrict__ bias,
                                             const float* __restrict__ dinv,
                                             const int* __restrict__ ptr,
                                             const unsigned short* __restrict__ esrc,
                                             const unsigned short* __restrict__ skipb,
                                             unsigned short* __restrict__ outb,
                                             int relu_res, int N) {
    int n = blockIdx.x * 4 + (threadIdx.x >> 6);
    if (n >= N) return;
    int l = threadIdx.x & 63;
    int grp = l >> 4, li = l & 15;
    const uint4* __restrict__ Gv = reinterpret_cast<const uint4*>(Gb);
    int beg = ptr[n], end = ptr[n + 1];
    float acc[8] = {};
    float t[8];
    int e = beg;
    for (; e + 8 <= end; e += 8) {
        int s0 = esrc[e + grp];
        int s1 = esrc[e + 4 + grp];
        uint4 g0 = Gv[(size_t)s0 * 16 + li];
        uint4 g1 = Gv[(size_t)s1 * 16 + li];
        unp8(g0, t);
        #pragma unroll
        for (int j = 0; j < 8; ++j) acc[j] += t[j];
        unp8(g1, t);
        #pragma unroll
        for (int j = 0; j < 8; ++j) acc[j] += t[j];
    }
    for (; e + 4 <= end; e += 4) {
        int s0 = esrc[e + grp];
        uint4 g0 = Gv[(size_t)s0 * 16 + li];
        unp8(g0, t);
        #pragma unroll
        for (int j = 0; j < 8; ++j) acc[j] += t[j];
    }
    int rem = end - e;
    if (grp < rem) {
        int s0 = esrc[e + grp];
        uint4 g0 = Gv[(size_t)s0 * 16 + li];
        unp8(g0, t);
        #pragma unroll
        for (int j = 0; j < 8; ++j) acc[j] += t[j];
    }
    // combine 4 edge-groups
    #pragma unroll
    for (int j = 0; j < 8; ++j) {
        acc[j] += __shfl_xor(acc[j], 16);
        acc[j] += __shfl_xor(acc[j], 32);
    }
    if (grp == 0) {
        float di = dinv[n];
        uint4 gu = Gv[(size_t)n * 16 + li];
        float gs[8];
        unp8(gu, gs);
        const float4* b4 = reinterpret_cast<const float4*>(bias);
        float4 ba = b4[li * 2], bb = b4[li * 2 + 1];
        float bv[8] = {ba.x, ba.y, ba.z, ba.w, bb.x, bb.y, bb.z, bb.w};
        float v[8];
        #pragma unroll
        for (int j = 0; j < 8; ++j) v[j] = fmaf(di, acc[j] + gs[j], bv[j]);
        if (relu_res) {
            uint4 su = reinterpret_cast<const uint4*>(skipb)[(size_t)n * 16 + li];
            float ss[8];
            unp8(su, ss);
            #pragma unroll
            for (int j = 0; j < 8; ++j) v[j] = fmaxf(v[j], 0.f) + ss[j];
        }
        uint4 o;
        o.x = (unsigned)f2bf(v[0]) | ((unsigned)f2bf(v[1]) << 16);
        o.y = (unsigned)f2bf(v[2]) | ((unsigned)f2bf(v[3]) << 16);
        o.z = (unsigned)f2bf(v[4]) | ((unsigned)f2bf(v[5]) << 16);
        o.w = (unsigned)f2bf(v[6]) | ((unsigned)f2bf(v[7]) << 16);
        reinterpret_cast<uint4*>(outb)[(size_t)n * 16 + li] = o;
    }
}

// ---------------------------------------------------------------------------
// final classifier, bf16 H input, fp32 Wf/compute/output (outs padded 40->64)
__global__ __launch_bounds__(256) void k_final(const unsigned short* __restrict__ Hb,
                                               const float* __restrict__ Wf,
                                               const float* __restrict__ bf,
                                               float* __restrict__ out, int N) {
    __shared__ float Xs[16][68];
    __shared__ float Ws[16][64];
    int tid = threadIdx.x;
    int n0 = blockIdx.x * 64;
    int tx = tid & 15;
    int ty = tid >> 4;
    float acc[4][4] = {};
    for (int k0 = 0; k0 < DIM; k0 += 16) {
        {
            int j = tid >> 2, kq = tid & 3;
            int row = n0 + j;
            if (row >= N) row = N - 1;
            ushort4 x4 = *reinterpret_cast<const ushort4*>(&Hb[(size_t)row * DIM + k0 + kq * 4]);
            Xs[kq * 4 + 0][j] = bf2f(x4.x);
            Xs[kq * 4 + 1][j] = bf2f(x4.y);
            Xs[kq * 4 + 2][j] = bf2f(x4.z);
            Xs[kq * 4 + 3][j] = bf2f(x4.w);
        }
        {
            int o = tid >> 2, kq = tid & 3;
            int om = o < NCLS ? o : o - NCLS;
            const float4 w4 = *reinterpret_cast<const float4*>(&Wf[(size_t)om * DIM + k0 + kq * 4]);
            Ws[kq * 4 + 0][o] = w4.x;
            Ws[kq * 4 + 1][o] = w4.y;
            Ws[kq * 4 + 2][o] = w4.z;
            Ws[kq * 4 + 3][o] = w4.w;
        }
        __syncthreads();
        #pragma unroll
        for (int k = 0; k < 16; ++k) {
            float4 w = *reinterpret_cast<const float4*>(&Ws[k][tx * 4]);
            float4 x = *reinterpret_cast<const float4*>(&Xs[k][ty * 4]);
            float xv[4] = {x.x, x.y, x.z, x.w};
            #pragma unroll
            for (int i = 0; i < 4; ++i) {
                acc[i][0] = fmaf(xv[i], w.x, acc[i][0]);
                acc[i][1] = fmaf(xv[i], w.y, acc[i][1]);
                acc[i][2] = fmaf(xv[i], w.z, acc[i][2]);
                acc[i][3] = fmaf(xv[i], w.w, acc[i][3]);
            }
        }
        __syncthreads();
    }
    if (tx >= 10) return;
    float4 b4 = make_float4(bf[tx * 4], bf[tx * 4 + 1], bf[tx * 4 + 2], bf[tx * 4 + 3]);
    #pragma unroll
    for (int i = 0; i < 4; ++i) {
        int row = n0 + ty * 4 + i;
        if (row < N) {
            float* op = &out[(size_t)row * NCLS + tx * 4];
            op[0] = acc[i][0] + b4.x;
            op[1] = acc[i][1] + b4.y;
            op[2] = acc[i][2] + b4.z;
            op[3] = acc[i][3] + b4.w;
        }
    }
}

// ---------------------------------------------------------------------------
extern "C" void kernel_launch(void* const* d_in, const int* in_sizes, int n_in,
                              void* d_out, int out_size, void* d_ws, size_t ws_size,
                              hipStream_t stream) {
    (void)in_sizes; (void)n_in; (void)out_size; (void)ws_size;
    const float* X  = (const float*)d_in[0];
    const int*   A  = (const int*)d_in[1];
    const float* W0 = (const float*)d_in[2];
    const float* b0 = (const float*)d_in[3];
    const float* W1 = (const float*)d_in[4];
    const float* b1 = (const float*)d_in[5];
    const float* W2 = (const float*)d_in[6];
    const float* b2 = (const float*)d_in[7];
    const float* W3 = (const float*)d_in[8];
    const float* b3 = (const float*)d_in[9];
    const float* Wf = (const float*)d_in[10];
    const float* bf = (const float*)d_in[11];
    float* out = (float*)d_out;

    char* base_ws = (char*)d_ws;
    size_t off = 0;
    auto alloc = [&](size_t bytes) -> char* {
        char* p = base_ws + off;
        off = (off + bytes + 255) & ~(size_t)255;
        return p;
    };
    float* scale_inv = (float*)alloc(4 * sizeof(float));
    int*   deg    = (int*)alloc(N_NODES_C * sizeof(int));
    int*   fill   = (int*)alloc(N_NODES_C * sizeof(int));
    int*   ptr    = (int*)alloc((N_NODES_C + 1) * sizeof(int));
    float* dinv   = (float*)alloc(N_NODES_C * sizeof(float));
    int*   part   = (int*)alloc(SCAN_NB * sizeof(int));
    int*   gcount = (int*)alloc(NBUK * sizeof(int));
    unsigned int*   ebuk = (unsigned int*)alloc((size_t)NBUK * BCAP * sizeof(unsigned int));
    unsigned short* esrc = (unsigned short*)alloc((size_t)N_EDGES_C * sizeof(unsigned short));
    unsigned short* Gb  = (unsigned short*)alloc((size_t)N_NODES_C * DIM * sizeof(unsigned short));
    unsigned short* Xb  = (unsigned short*)alloc((size_t)N_NODES_C * DIM * sizeof(unsigned short));
    unsigned short* Hb1 = (unsigned short*)alloc((size_t)N_NODES_C * DIM * sizeof(unsigned short));
    unsigned short* Hb2 = (unsigned short*)alloc((size_t)N_NODES_C * DIM * sizeof(unsigned short));
    unsigned short* Wb  = (unsigned short*)alloc((size_t)4 * DIM * DIM * sizeof(unsigned short));

    hipMemsetAsync(gcount, 0, NBUK * sizeof(int), stream);

    k_pre<<<F2B_NB + 64 + 4, 256, 0, stream>>>(X, W0, W1, W2, W3, Xb, Wb, scale_inv);
    k_bucket<<<(N_EDGES_C + 1023) / 1024, 256, 0, stream>>>(A, gcount, ebuk, N_EDGES_C);
    k_degb<<<NBUK, 256, 0, stream>>>(ebuk, gcount, deg);
    k_scan_part<<<SCAN_NB, 256, 0, stream>>>(deg, part, dinv, fill, N_NODES_C);
    k_scan_final<<<SCAN_NB, 256, 0, stream>>>(deg, part, ptr, N_NODES_C, SCAN_NB);
    k_fillb<<<NBUK * (BCAP / 1024), 256, 0, stream>>>(ebuk, gcount, ptr, fill, esrc);

    const int gemm_grid = (N_NODES_C + 63) / 64;
    const int agg_grid  = (N_NODES_C + 3) / 4;

    // layer 0
    k_gemm_mfma<<<gemm_grid, 256, 0, stream>>>(Xb, Wb + 0 * DIM * DIM, scale_inv + 0, dinv, Gb, N_NODES_C);
    k_agg<<<agg_grid, 256, 0, stream>>>(Gb, b0, dinv, ptr, esrc, nullptr, Hb1, 0, N_NODES_C);
    // layer 1
    k_gemm_mfma<<<gemm_grid, 256, 0, stream>>>(Hb1, Wb + 1 * DIM * DIM, scale_inv + 1, dinv, Gb, N_NODES_C);
    k_agg<<<agg_grid, 256, 0, stream>>>(Gb, b1, dinv, ptr, esrc, Hb1, Hb2, 1, N_NODES_C);
    // layer 2
    k_gemm_mfma<<<gemm_grid, 256, 0, stream>>>(Hb2, Wb + 2 * DIM * DIM, scale_inv + 2, dinv, Gb, N_NODES_C);
    k_agg<<<agg_grid, 256, 0, stream>>>(Gb, b2, dinv, ptr, esrc, Hb2, Hb1, 1, N_NODES_C);
    // layer 3
    k_gemm_mfma<<<gemm_grid, 256, 0, stream>>>(Hb1, Wb + 3 * DIM * DIM, scale_inv + 3, dinv, Gb, N_NODES_C);
    k_agg<<<agg_grid, 256, 0, stream>>>(Gb, b3, dinv, ptr, esrc, Hb1, Hb2, 1, N_NODES_C);
    // final classifier
    k_final<<<(N_NODES_C + 63) / 64, 256, 0, stream>>>(Hb2, Wf, bf, out, N_NODES_C);
}